// Round 4
// baseline (205.545 us; speedup 1.0000x reference)
//
#include <hip/hip_runtime.h>
#include <hip/hip_bf16.h>

// Reduction of the reference (h0 = 0):
//   z  = sigmoid(x @ Wz + bz),  t = tanh(x @ Wh + bh),  h = (1-z)*t
//   out= sigmoid(relu(h @ fc1) @ fc2)       (w_r/b_r, edge_index dead)
// Memory-bound on x: 102.4 MB fp32 (~50 MB HBM + ~52 MB L3-hit per dispatch).
//
// R8 theory: R4-R7 all ~63-67 us, every pipe <12% => latency-bound.
// VGPR_Count=68 proves R7's register double-buffer never existed (bufA+bufB
// alone need 64 VGPRs) -> ~6 loads in flight/wave -> 780 GB/s.
// Fix: wave-private LDS staging of A via global_load_lds (width 16):
//  - zero data VGPRs (DMA direct to LDS), so the pipeline can't be
//    register-allocated away;
//  - coalesced staging (each 1KB DMA = 16 rows x 64 contiguous bytes);
//  - wave-private buffers => ZERO barriers in the K-loop; ordering is pure
//    counted s_waitcnt vmcnt(2) (never 0 until the last chunk);
//  - XOR slot-swizzle baked into the per-lane GLOBAL src (linear LDS dest,
//    swizzled read addr) => fragment ds_reads are 2-way (free) not 8-way;
//  - B frags linear in LDS (1 KB groups, lane*16 b128 reads conflict-free),
//    staged once via global_load_lds, single __syncthreads in the kernel;
//  - epilogue H tile aliased into the wave's own A region (wave-private,
//    DMA fully drained by final vmcnt(0)) => LDS 16K+32K = 48 KB
//    => 3 blocks/CU, grid 782 ~ 768 resident (one round).
// R9/R10: "container failed twice" x2 — turned out to be masking a plain
// COMPILE ERROR (R11 diagnostic): `ab` was const char* but is the DMA
// *destination* in the c+2 prefetch. Lesson: infra errors without a compile
// log may be compile failures; a 2s compile check would have caught it.
// R11: one-token fix (char* ab). Algorithm identical to R8.

#define NF     256
#define TILE   32            // nodes per wave
#define WPB    4             // waves per block
#define MB     (TILE * WPB)  // 128 nodes per block
#define NTHR   256
#define NCHUNK 16            // K chunks of 16 floats
#define ABUF   2048          // bytes per A chunk buffer (32 rows x 64 B)

typedef __attribute__((ext_vector_type(8)))  short  short8;
typedef __attribute__((ext_vector_type(16))) float  floatx16;

__device__ __forceinline__ unsigned f2bf(float f) {
    __hip_bfloat16 h = __float2bfloat16(f);   // RNE
    return (unsigned)*(unsigned short*)&h;
}
__device__ __forceinline__ float fast_sigmoid(float v) {
    return 1.0f / (1.0f + __expf(-v));
}
__device__ __forceinline__ float fast_tanh(float v) {
    return 1.0f - 2.0f / (1.0f + __expf(2.0f * v));
}
__device__ __forceinline__ void dma16(const void* g, void* l) {
    __builtin_amdgcn_global_load_lds(
        (const __attribute__((address_space(1))) unsigned int*)g,
        (__attribute__((address_space(3))) unsigned int*)l,
        16, 0, 0);
}

// ---- prep: fold w[0]+w[1], emit bf16 in 32x32x16 B-fragment order:
// Wf[((kt*2+nt)*64 + lane)*8 + j] = W[kt*16 + (lane>>5)*8 + j][nt*32 + (lane&31)]
__global__ void prep_W(const float* __restrict__ wz,   // (2, 288, 32)
                       const float* __restrict__ wh,   // (2, 288, 32)
                       unsigned short* __restrict__ Wf) // 16*2*64*8 bf16
{
    int idx = blockIdx.x * blockDim.x + threadIdx.x;   // 0 .. 16383
    if (idx >= NF * 64) return;
    int j    = idx & 7;
    int lane = (idx >> 3) & 63;
    int nt   = (idx >> 9) & 1;
    int kt   = idx >> 10;                  // 0..15
    int k = kt * 16 + (lane >> 5) * 8 + j; // 0..255
    int o = nt * 32 + (lane & 31);         // 0..63
    const int PLANE = 288 * 32;
    float v;
    if (o < 32) v = wz[k * 32 + o]        + wz[PLANE + k * 32 + o];
    else        v = wh[k * 32 + (o - 32)] + wh[PLANE + k * 32 + (o - 32)];
    Wf[idx] = (unsigned short)f2bf(v);
}

__global__ void __launch_bounds__(NTHR, 3)
rgcn_main(const float* __restrict__ x,     // [N, 256]
          const unsigned short* __restrict__ Wf, // B-frags (ws, 32 KB)
          const float* __restrict__ bz,    // [32]
          const float* __restrict__ bh,    // [32]
          const float* __restrict__ fc1w,  // [32][32] (in,out)
          const float* __restrict__ fc1b,  // [32]
          const float* __restrict__ fc2w,  // [32]
          const float* __restrict__ fc2b,  // [1]
          float* __restrict__ out,         // [N]
          int n_nodes)
{
    __shared__ __align__(16) char SA [WPB * 2 * ABUF];  // 16 KB: A dbuf + H epi
    __shared__ __align__(16) char SBf[32 * 1024];       // 32 KB: B frags

    const int tid   = threadIdx.x;
    const int lane  = tid & 63;
    const int wave  = tid >> 6;              // 0..3
    const int node0 = blockIdx.x * MB + wave * TILE;

    // ---- stage B via global_load_lds: wave w -> groups w*8 .. w*8+7.
    // dest linear (uniform base + lane*16), src coalesced 1 KB per inst.
    {
        const char* wsrc = (const char*)Wf;
#pragma unroll
        for (int i = 0; i < 8; ++i) {
            int g = wave * 8 + i;
            dma16(wsrc + (size_t)g * 1024 + lane * 16, SBf + g * 1024);
        }
    }

    // epilogue operands preloaded here so loop vmcnt counting stays exact
    const int nc  = lane & 31;
    const float bzn = bz[nc];
    const float bhn = bh[nc];

    asm volatile("s_waitcnt vmcnt(0)" ::: "memory");
    __syncthreads();   // the only block-wide barrier (B visible to all waves)

    // ---- A staging geometry (wave-private).
    // chunk c = K floats [c*16, c*16+16) for this wave's 32 rows; 2 KB.
    // DMA inst i in {0,1}: lane l -> row i*16 + (l>>2), 16-B slot
    //   (l&3) ^ ((l>>3)&3)   (XOR pre-swizzle on the GLOBAL side; LDS linear)
    const int srow = lane >> 2;                       // 0..15
    const int slot = (lane & 3) ^ ((lane >> 3) & 3);  // swizzled src slot
    int r0 = node0 + srow;       if (r0 >= n_nodes) r0 = n_nodes - 1;
    int r1 = node0 + 16 + srow;  if (r1 >= n_nodes) r1 = n_nodes - 1;
    const char* a0p = (const char*)x + (size_t)r0 * (NF * 4) + slot * 16;
    const char* a1p = (const char*)x + (size_t)r1 * (NF * 4) + slot * 16;
    char* aw = SA + wave * (2 * ABUF);                // this wave's 4 KB

    // fragment read offsets (swizzled to match): row m, logical slots
    // s0=(lane>>5)*2, s0+1 ; physical slot = s ^ ((m>>1)&3) -> 2-way banks
    const int m   = lane & 31;
    const int rsw = (m >> 1) & 3;
    const int s0  = (lane >> 5) * 2;
    const int ra0 = m * 64 + (((s0    ) ^ rsw) << 4);
    const int ra1 = m * 64 + (((s0 + 1) ^ rsw) << 4);
    const char* bl = SBf + lane * 16;

    // prologue: issue chunks 0 and 1 (2 DMA each)
    dma16(a0p +  0, aw);          dma16(a1p +  0, aw + 1024);
    dma16(a0p + 64, aw + ABUF);   dma16(a1p + 64, aw + ABUF + 1024);

    floatx16 acc0 = {};                      // z cols (nt=0)
    floatx16 acc1 = {};                      // h cols (nt=1)

#pragma unroll
    for (int c = 0; c < NCHUNK; ++c) {
        // chunk c ready when <=2 (newer) loads remain outstanding
        if (c < NCHUNK - 1) asm volatile("s_waitcnt vmcnt(2)" ::: "memory");
        else                asm volatile("s_waitcnt vmcnt(0)" ::: "memory");
        __builtin_amdgcn_sched_barrier(0);

        char* ab = aw + (c & 1) * ABUF;      // R11 fix: non-const (DMA dest)
        float4 f0 = *(const float4*)(ab + ra0);
        float4 f1 = *(const float4*)(ab + ra1);
        uint4  vb0 = *(const uint4*)(bl + (size_t)(2 * c    ) * 1024);
        uint4  vb1 = *(const uint4*)(bl + (size_t)(2 * c + 1) * 1024);

        union { short8 s; unsigned u[4]; } A, B0, B1;
        A.u[0] = f2bf(f0.x) | (f2bf(f0.y) << 16);
        A.u[1] = f2bf(f0.z) | (f2bf(f0.w) << 16);
        A.u[2] = f2bf(f1.x) | (f2bf(f1.y) << 16);
        A.u[3] = f2bf(f1.z) | (f2bf(f1.w) << 16);
        B0.u[0] = vb0.x; B0.u[1] = vb0.y; B0.u[2] = vb0.z; B0.u[3] = vb0.w;
        B1.u[0] = vb1.x; B1.u[1] = vb1.y; B1.u[2] = vb1.z; B1.u[3] = vb1.w;

        acc0 = __builtin_amdgcn_mfma_f32_32x32x16_bf16(A.s, B0.s, acc0, 0, 0, 0);
        acc1 = __builtin_amdgcn_mfma_f32_32x32x16_bf16(A.s, B1.s, acc1, 0, 0, 0);

        if (c + 2 < NCHUNK) {
            // pin DMA issue BELOW this chunk's ds_reads (same buffer parity)
            __builtin_amdgcn_sched_barrier(0);
            dma16(a0p + (size_t)(c + 2) * 64, ab);
            dma16(a1p + (size_t)(c + 2) * 64, ab + 1024);
        }
    }

    // ---- epilogue: gates in-register (C/D: col=lane&31,
    // row=(reg&3)+8*(reg>>2)+4*(lane>>5)); H tile aliased into this wave's
    // A region (4 KB, DMA drained by the final vmcnt(0)); XOR-swizzled
    // (slot ^= row&7) so the transpose read is 2-way, not 16-way banked.
    float* Hw = (float*)aw;
#pragma unroll
    for (int r = 0; r < 16; ++r) {
        int row = (r & 3) + 8 * (r >> 2) + 4 * (lane >> 5);
        float z = fast_sigmoid(acc0[r] + bzn);
        float t = fast_tanh   (acc1[r] + bhn);
        int boff = row * 128 + ((((nc >> 2) ^ (row & 7)) << 4) | ((nc & 3) << 2));
        *(float*)((char*)Hw + boff) = (1.0f - z) * t;
    }
    // within-wave DS ordering: drain writes before cross-lane reads
    asm volatile("s_waitcnt lgkmcnt(0)" ::: "memory");

    const int nl   = lane & 31;
    const int half = lane >> 5;
    float h[32];
#pragma unroll
    for (int q = 0; q < 8; ++q) {
        int boff = nl * 128 + ((q ^ (nl & 7)) << 4);
        float4 v = *(const float4*)((char*)Hw + boff);
        h[q * 4 + 0] = v.x; h[q * 4 + 1] = v.y;
        h[q * 4 + 2] = v.z; h[q * 4 + 3] = v.w;
    }
    float part = 0.0f;
    for (int jj = 0; jj < 16; ++jj) {
        int j = (half << 4) + jj;            // 2 addrs/wave -> broadcastish
        float s = fc1b[j];
#pragma unroll
        for (int o = 0; o < 32; ++o)
            s = fmaf(h[o], fc1w[o * 32 + j], s);
        part = fmaf(fmaxf(s, 0.0f), fc2w[j], part);
    }
    part += __shfl_xor(part, 32);            // combine the two j-halves
    if (half == 0) {
        int gn = node0 + nl;
        if (gn < n_nodes)
            out[gn] = fast_sigmoid(part + fc2b[0]);   // 32-lane coalesced
    }
}

extern "C" void kernel_launch(void* const* d_in, const int* in_sizes, int n_in,
                              void* d_out, int out_size, void* d_ws, size_t ws_size,
                              hipStream_t stream) {
    // 0:x 1:edge_index(dead) 2:w_z 3:b_z 4:w_r(dead) 5:b_r(dead)
    // 6:w_h 7:b_h 8:fc1_w 9:fc1_b 10:fc2_w 11:fc2_b
    const float* x    = (const float*)d_in[0];
    const float* wz   = (const float*)d_in[2];
    const float* bz   = (const float*)d_in[3];
    const float* wh   = (const float*)d_in[6];
    const float* bh   = (const float*)d_in[7];
    const float* fc1w = (const float*)d_in[8];
    const float* fc1b = (const float*)d_in[9];
    const float* fc2w = (const float*)d_in[10];
    const float* fc2b = (const float*)d_in[11];
    float* out = (float*)d_out;
    unsigned short* Wf = (unsigned short*)d_ws;   // 32 KB of B-fragments

    const int n = in_sizes[0] / NF;   // 100000

    prep_W<<<(NF * 64 + 255) / 256, 256, 0, stream>>>(wz, wh, Wf);
    rgcn_main<<<(n + MB - 1) / MB, NTHR, 0, stream>>>(
        x, Wf, bz, bh, fc1w, fc1b, fc2w, fc2b, out, n);
}

// Round 5
// 201.615 us; speedup vs baseline: 1.0195x; 1.0195x over previous
//
#include <hip/hip_runtime.h>
#include <hip/hip_bf16.h>

// Reduction of the reference (h0 = 0):
//   z  = sigmoid(x @ Wz + bz),  t = tanh(x @ Wh + bh),  h = (1-z)*t
//   out= sigmoid(relu(h @ fc1) @ fc2)       (w_r/b_r, edge_index dead)
// Compulsory traffic: x = 102.4 MB fp32 read once (floor ~16.3 us @6.3 TB/s).
//
// R12 theory: R0/R4-R8 (register dbuf, barriered LDS, wave-private DMA dbuf)
// ALL land at ~65 us, ~790 GB/s HBM, every pipe <12%. R8 had ~36 KB/CU of
// DMA outstanding (Little's law: ~100 GB/s/CU capacity) yet moved nothing
// -> NOT a pipeline-depth problem; the SERVICE rate for the shared access
// pattern is capped (~1.6 TB/s chip). Invariant across all variants: x is
// read as 64-B runs scattered over 16-32 rows per instruction (half a
// 128-B line, 16 line-splits per gather). R12 changes ONE variable: run
// length 64->128 B, line-aligned. Chunk = 32 k-floats x 32 rows (4 KB);
// each DMA instr = 8 rows x 128 CONTIGUOUS bytes. Triple-buffered chunks
// (vmcnt(8) steady, never 0 until last), zero K-loop barriers, XOR
// slot-swizzle p = s ^ (row&7) on BOTH global src and frag read (A-frag
// ds_reads 4-way, LDS not critical). LDS 48K A + 32K B = 80 KB -> 2
// blocks/CU. If this sits at 65 us too, contiguity is falsified -> pivot
// to two-pass layout transform via d_ws.

#define NF     256
#define TILE   32            // nodes per wave
#define WPB    4             // waves per block
#define MB     (TILE * WPB)  // 128 nodes per block
#define NTHR   256
#define NCHUNK 8             // K chunks of 32 floats (128 B per row)
#define NBUF   3             // chunk buffers in flight
#define ABUF   4096          // bytes per A chunk buffer (32 rows x 128 B)

typedef __attribute__((ext_vector_type(8)))  short  short8;
typedef __attribute__((ext_vector_type(16))) float  floatx16;

__device__ __forceinline__ unsigned f2bf(float f) {
    __hip_bfloat16 h = __float2bfloat16(f);   // RNE
    return (unsigned)*(unsigned short*)&h;
}
__device__ __forceinline__ float fast_sigmoid(float v) {
    return 1.0f / (1.0f + __expf(-v));
}
__device__ __forceinline__ float fast_tanh(float v) {
    return 1.0f - 2.0f / (1.0f + __expf(2.0f * v));
}
__device__ __forceinline__ void dma16(const void* g, void* l) {
    __builtin_amdgcn_global_load_lds(
        (const __attribute__((address_space(1))) unsigned int*)g,
        (__attribute__((address_space(3))) unsigned int*)l,
        16, 0, 0);
}

// ---- prep: fold w[0]+w[1], emit bf16 in 32x32x16 B-fragment order:
// Wf[((kt*2+nt)*64 + lane)*8 + j] = W[kt*16 + (lane>>5)*8 + j][nt*32 + (lane&31)]
__global__ void prep_W(const float* __restrict__ wz,   // (2, 288, 32)
                       const float* __restrict__ wh,   // (2, 288, 32)
                       unsigned short* __restrict__ Wf) // 16*2*64*8 bf16
{
    int idx = blockIdx.x * blockDim.x + threadIdx.x;   // 0 .. 16383
    if (idx >= NF * 64) return;
    int j    = idx & 7;
    int lane = (idx >> 3) & 63;
    int nt   = (idx >> 9) & 1;
    int kt   = idx >> 10;                  // 0..15
    int k = kt * 16 + (lane >> 5) * 8 + j; // 0..255
    int o = nt * 32 + (lane & 31);         // 0..63
    const int PLANE = 288 * 32;
    float v;
    if (o < 32) v = wz[k * 32 + o]        + wz[PLANE + k * 32 + o];
    else        v = wh[k * 32 + (o - 32)] + wh[PLANE + k * 32 + (o - 32)];
    Wf[idx] = (unsigned short)f2bf(v);
}

// Issue one 4-KB chunk (4 DMA instrs, each 8 rows x 128 contiguous bytes)
#define ISSUE_CHUNK(cc, buf)                                        \
    do {                                                            \
        dma16(ap0 + (size_t)(cc) * 128, (buf));                     \
        dma16(ap1 + (size_t)(cc) * 128, (buf) + 1024);              \
        dma16(ap2 + (size_t)(cc) * 128, (buf) + 2048);              \
        dma16(ap3 + (size_t)(cc) * 128, (buf) + 3072);              \
    } while (0)

__global__ void __launch_bounds__(NTHR, 2)
rgcn_main(const float* __restrict__ x,     // [N, 256]
          const unsigned short* __restrict__ Wf, // B-frags (ws, 32 KB)
          const float* __restrict__ bz,    // [32]
          const float* __restrict__ bh,    // [32]
          const float* __restrict__ fc1w,  // [32][32] (in,out)
          const float* __restrict__ fc1b,  // [32]
          const float* __restrict__ fc2w,  // [32]
          const float* __restrict__ fc2b,  // [1]
          float* __restrict__ out,         // [N]
          int n_nodes)
{
    __shared__ __align__(16) char SA [WPB * NBUF * ABUF]; // 48 KB: A tbuf + H epi
    __shared__ __align__(16) char SBf[32 * 1024];         // 32 KB: B frags

    const int tid   = threadIdx.x;
    const int lane  = tid & 63;
    const int wave  = tid >> 6;              // 0..3
    const int node0 = blockIdx.x * MB + wave * TILE;

    // ---- stage B via global_load_lds: wave w -> groups w*8 .. w*8+7.
    {
        const char* wsrc = (const char*)Wf;
#pragma unroll
        for (int i = 0; i < 8; ++i) {
            int g = wave * 8 + i;
            dma16(wsrc + (size_t)g * 1024 + lane * 16, SBf + g * 1024);
        }
    }

    // epilogue operands preloaded here so loop vmcnt counting stays exact
    const int nc  = lane & 31;
    const float bzn = bz[nc];
    const float bhn = bh[nc];

    asm volatile("s_waitcnt vmcnt(0)" ::: "memory");
    __syncthreads();   // the only block-wide barrier (B visible to all waves)

    // ---- A staging geometry (wave-private).
    // chunk c = K floats [c*32, c*32+32) (128 B) for the wave's 32 rows.
    // DMA instr i (0..3): lane l -> row 8i + (l>>3), 16-B slot l&7 in LDS
    // (linear dest). Global src slot = (l&7) ^ (l>>3)  => LDS[m][p] holds
    // global slot p ^ (m&7); each 8-lane group covers ONE aligned 128-B
    // run of one row (XOR permutes within the run only).
    const int rg   = lane >> 3;                      // 0..7 row-in-group
    const int gslt = (lane & 7) ^ rg;                // pre-swizzled src slot
    int r0 = node0 +      rg; if (r0 >= n_nodes) r0 = n_nodes - 1;
    int r1 = node0 +  8 + rg; if (r1 >= n_nodes) r1 = n_nodes - 1;
    int r2 = node0 + 16 + rg; if (r2 >= n_nodes) r2 = n_nodes - 1;
    int r3 = node0 + 24 + rg; if (r3 >= n_nodes) r3 = n_nodes - 1;
    const char* ap0 = (const char*)x + (size_t)r0 * (NF * 4) + gslt * 16;
    const char* ap1 = (const char*)x + (size_t)r1 * (NF * 4) + gslt * 16;
    const char* ap2 = (const char*)x + (size_t)r2 * (NF * 4) + gslt * 16;
    const char* ap3 = (const char*)x + (size_t)r3 * (NF * 4) + gslt * 16;
    char* aw = SA + wave * (NBUF * ABUF);            // this wave's 12 KB

    // fragment read: k-step kk in {0,1}; lane needs floats [16kk+8h, +8)
    // of row m = logical slots s0=4kk+2h, s0+1; physical slot = s ^ (m&7)
    const int m   = lane & 31;
    const int h   = lane >> 5;
    const int rsw = m & 7;
    const char* bl = SBf + lane * 16;

    // prologue: issue chunks 0,1,2 (12 DMA)
    ISSUE_CHUNK(0, aw);
    ISSUE_CHUNK(1, aw + ABUF);
    ISSUE_CHUNK(2, aw + 2 * ABUF);

    floatx16 acc0 = {};                      // z cols (nt=0)
    floatx16 acc1 = {};                      // h cols (nt=1)

#pragma unroll
    for (int c = 0; c < NCHUNK; ++c) {
        // chunk c ready when only the 2 newer chunks (8 loads) remain
        if (c < 6)       asm volatile("s_waitcnt vmcnt(8)" ::: "memory");
        else if (c == 6) asm volatile("s_waitcnt vmcnt(4)" ::: "memory");
        else             asm volatile("s_waitcnt vmcnt(0)" ::: "memory");
        __builtin_amdgcn_sched_barrier(0);

        char* ab = aw + (c % NBUF) * ABUF;
#pragma unroll
        for (int kk = 0; kk < 2; ++kk) {
            int sA = 4 * kk + 2 * h;
            float4 f0 = *(const float4*)(ab + m * 128 + (((sA    ) ^ rsw) << 4));
            float4 f1 = *(const float4*)(ab + m * 128 + (((sA + 1) ^ rsw) << 4));
            int kt = 2 * c + kk;
            uint4 b0u = *(const uint4*)(bl + (size_t)(2 * kt    ) * 1024);
            uint4 b1u = *(const uint4*)(bl + (size_t)(2 * kt + 1) * 1024);

            union { short8 s; unsigned u[4]; } A, B0, B1;
            A.u[0] = f2bf(f0.x) | (f2bf(f0.y) << 16);
            A.u[1] = f2bf(f0.z) | (f2bf(f0.w) << 16);
            A.u[2] = f2bf(f1.x) | (f2bf(f1.y) << 16);
            A.u[3] = f2bf(f1.z) | (f2bf(f1.w) << 16);
            B0.u[0] = b0u.x; B0.u[1] = b0u.y; B0.u[2] = b0u.z; B0.u[3] = b0u.w;
            B1.u[0] = b1u.x; B1.u[1] = b1u.y; B1.u[2] = b1u.z; B1.u[3] = b1u.w;

            acc0 = __builtin_amdgcn_mfma_f32_32x32x16_bf16(A.s, B0.s, acc0, 0, 0, 0);
            acc1 = __builtin_amdgcn_mfma_f32_32x32x16_bf16(A.s, B1.s, acc1, 0, 0, 0);
        }

        if (c < NCHUNK - NBUF) {
            // pin DMA issue BELOW this chunk's ds_reads (same buffer)
            __builtin_amdgcn_sched_barrier(0);
            ISSUE_CHUNK(c + NBUF, ab);
        }
    }

    // ---- epilogue: gates in-register (C/D: col=lane&31,
    // row=(reg&3)+8*(reg>>2)+4*(lane>>5)); H tile aliased into this wave's
    // A region (4 KB of 12, DMA drained by the final vmcnt(0)); XOR-swizzled
    // (slot ^= row&7) so the transpose read is 2-way, not 16-way banked.
    float* Hw = (float*)aw;
#pragma unroll
    for (int r = 0; r < 16; ++r) {
        int row = (r & 3) + 8 * (r >> 2) + 4 * (lane >> 5);
        float z = fast_sigmoid(acc0[r] + bzn);
        float t = fast_tanh   (acc1[r] + bhn);
        int boff = row * 128 + ((((nc >> 2) ^ (row & 7)) << 4) | ((nc & 3) << 2));
        *(float*)((char*)Hw + boff) = (1.0f - z) * t;
    }
    // within-wave DS ordering: drain writes before cross-lane reads
    asm volatile("s_waitcnt lgkmcnt(0)" ::: "memory");

    const int nl   = lane & 31;
    const int half = lane >> 5;
    float hbuf[32];
#pragma unroll
    for (int q = 0; q < 8; ++q) {
        int boff = nl * 128 + ((q ^ (nl & 7)) << 4);
        float4 v = *(const float4*)((char*)Hw + boff);
        hbuf[q * 4 + 0] = v.x; hbuf[q * 4 + 1] = v.y;
        hbuf[q * 4 + 2] = v.z; hbuf[q * 4 + 3] = v.w;
    }
    float part = 0.0f;
    for (int jj = 0; jj < 16; ++jj) {
        int j = (half << 4) + jj;            // 2 addrs/wave -> broadcastish
        float s = fc1b[j];
#pragma unroll
        for (int o = 0; o < 32; ++o)
            s = fmaf(hbuf[o], fc1w[o * 32 + j], s);
        part = fmaf(fmaxf(s, 0.0f), fc2w[j], part);
    }
    part += __shfl_xor(part, 32);            // combine the two j-halves
    if (half == 0) {
        int gn = node0 + nl;
        if (gn < n_nodes)
            out[gn] = fast_sigmoid(part + fc2b[0]);   // 32-lane coalesced
    }
}

extern "C" void kernel_launch(void* const* d_in, const int* in_sizes, int n_in,
                              void* d_out, int out_size, void* d_ws, size_t ws_size,
                              hipStream_t stream) {
    // 0:x 1:edge_index(dead) 2:w_z 3:b_z 4:w_r(dead) 5:b_r(dead)
    // 6:w_h 7:b_h 8:fc1_w 9:fc1_b 10:fc2_w 11:fc2_b
    const float* x    = (const float*)d_in[0];
    const float* wz   = (const float*)d_in[2];
    const float* bz   = (const float*)d_in[3];
    const float* wh   = (const float*)d_in[6];
    const float* bh   = (const float*)d_in[7];
    const float* fc1w = (const float*)d_in[8];
    const float* fc1b = (const float*)d_in[9];
    const float* fc2w = (const float*)d_in[10];
    const float* fc2b = (const float*)d_in[11];
    float* out = (float*)d_out;
    unsigned short* Wf = (unsigned short*)d_ws;   // 32 KB of B-fragments

    const int n = in_sizes[0] / NF;   // 100000

    prep_W<<<(NF * 64 + 255) / 256, 256, 0, stream>>>(wz, wh, Wf);
    rgcn_main<<<(n + MB - 1) / MB, NTHR, 0, stream>>>(
        x, Wf, bz, bh, fc1w, fc1b, fc2w, fc2b, out, n);
}